// Round 9
// baseline (174.517 us; speedup 1.0000x reference)
//
#include <hip/hip_runtime.h>

#define B_ 4
#define N_ 2048
#define K_ 32
#define CIN_ 16
#define COUT_ 32
#define H_ 32
#define R_ (B_*N_*K_)      // 262144 rows through the weight-net
#define EPS_ 1e-5f
#define INVR_ (1.0f/(float)R_)
#define INVBN_ (1.0f/(float)(B_*N_))
#define LISTCAP 160
#define NSH 16             // stat shadows

typedef __attribute__((ext_vector_type(8)))  _Float16 f16x8;
typedef __attribute__((ext_vector_type(2)))  __fp16   hw16x2;   // builtin cvt_pkrtz return type
typedef __attribute__((ext_vector_type(2)))  _Float16 f16x2;
typedef __attribute__((ext_vector_type(16))) float    f32x16;

__device__ __forceinline__ float dot3f(float ax,float ay,float az,float bx,float by,float bz){
    return fmaf(az,bz, fmaf(ay,by, ax*bx));
}
__device__ __forceinline__ unsigned int pk2(float a, float b){   // packed f16 pair (RTZ)
    union { hw16x2 v; unsigned int u; } c;
    c.v = __builtin_amdgcn_cvt_pkrtz(a, b);
    return c.u;
}
__device__ __forceinline__ unsigned int pkmul(unsigned int a, unsigned int b){  // v_pk_mul_f16
    union { unsigned int u; f16x2 v; } x, y, r;
    x.u = a; y.u = b; r.v = x.v * y.v; return r.u;
}
// sum of NSH shadow accumulators
__device__ __forceinline__ float shsum(const float* __restrict__ p, int k){
    float s = 0.f;
    #pragma unroll
    for (int i = 0; i < NSH; ++i) s += p[i*32 + k];
    return s;
}

// ---- prep0: xs4g[b*N+n] = (x,y,z,|p|^2); pf16 = f16-packed points; zero stats ----
__global__ __launch_bounds__(256) void k_prep0(const float* __restrict__ xyz, const float* __restrict__ points,
                                               float4* __restrict__ xs4g, unsigned int* __restrict__ pf16,
                                               float* __restrict__ st){
    int flat = blockIdx.x*256 + threadIdx.x;      // 288 blocks x 256 = 73728 = 8192 + 65536
    if (flat < 8192){
        float x = xyz[3*flat], y = xyz[3*flat+1], z = xyz[3*flat+2];
        xs4g[flat] = make_float4(x, y, z, dot3f(x,y,z,x,y,z));
    } else {
        int p = flat - 8192;
        pf16[p] = pk2(points[2*p], points[2*p+1]);
    }
    if (blockIdx.x == 0){
        for (int j = threadIdx.x; j < 1280; j += 256) st[j] = 0.f;
    }
}

// ---------------- KNN: 2 WAVES per query (latency-chain halved), wave-pair-autonomous ----------------
// R5's 1-wave/query variant is latency-bound at ~43us (VALUBusy 31-40%, HBM 1%, occ 50%).
// Split: block = 4 waves = 2 queries; pair p = w>>1, sub-wave ws = w&1 takes candidates
// c = j*128 + ws*64 + lane (16/lane). Histogram shared per pair (LDS atomics + s_barrier syncs,
// NO device fences -- R2/R3/R8 lesson). Select is recomputed redundantly per wave (deterministic).
// Compaction: count-pass -> cross-wave base -> store-pass (dense, order-free for rank-select).
// fv[16] fits (256,7) cap-72 without the R4 fv[32] spill. LDS 11KB.
__global__ __launch_bounds__(256,7) void k_knn(const float4* __restrict__ xs4g,
                                               const float* __restrict__ W1, const float* __restrict__ b1,
                                               int* __restrict__ idx_out,
                                               float* __restrict__ s1sh, float* __restrict__ q1sh,
                                               unsigned int* __restrict__ h1f){
    __shared__ unsigned int hist[2][512][2];          // 8 KB: per-pair 512 buckets x2 replicas
    __shared__ unsigned long long lst[2][LISTCAP];    // 2.5 KB
    __shared__ int kidx[2][K_];                       // 256 B
    __shared__ unsigned int cntW[2][2];

    const int tid  = threadIdx.x;
    const int w    = tid >> 6;
    const int lane = tid & 63;
    const int half = lane >> 5;
    const int p    = w >> 1;            // wave-pair = local query slot
    const int ws   = w & 1;             // sub-wave within pair
    const int qg   = blockIdx.x*2 + p;  // global query id (2 divides N_, never crosses batch)
    const int b    = qg >> 11;
    const int q    = qg & (N_-1);
    const int bN   = b * N_;
    unsigned int* hw = &hist[p][0][0];

    // zero hist: 256 uint4 per pair / 128 lanes = 2 each
    {
        const uint4 z4 = make_uint4(0,0,0,0);
        uint4* h4 = (uint4*)hw;
        int t2 = ws*64 + lane;
        h4[t2] = z4; h4[128 + t2] = z4;
    }
    __syncthreads();

    const float4 qp = xs4g[bN + q];
    const float qx = qp.x, qy = qp.y, qz = qp.z, sqq = qp.w;

    // pass 1: 16 candidates/lane, cache d-bits, linear histogram
    unsigned int fv[16];
    #pragma unroll
    for (int j = 0; j < 16; ++j){
        int c = j*128 + ws*64 + lane;
        float4 pt = xs4g[bN + c];
        float d = fmaf(-2.0f, dot3f(qx,qy,qz, pt.x,pt.y,pt.z), sqq) + pt.w;
        fv[j] = __float_as_uint(d);
        unsigned int u1 = __float_as_uint(d + 1.0f);
        unsigned int key = (u1 <= 0x3F800000u) ? 0u : ((u1 - 0x3F800000u) >> 15);
        key = key > 511u ? 511u : key;
        atomicAdd(&hw[key*2 + (lane & 1)], 1u);
    }
    __syncthreads();

    // select: smallest bucket with cumulative >= K (redundant per wave, deterministic)
    unsigned int g[8];
    #pragma unroll
    for (int t = 0; t < 4; ++t){
        uint4 h = ((const uint4*)hw)[lane*4 + t];
        g[2*t]   = h.x + h.y;
        g[2*t+1] = h.z + h.w;
    }
    unsigned int gs = 0;
    #pragma unroll
    for (int t = 0; t < 8; ++t) gs += g[t];
    unsigned int cum = gs;
    #pragma unroll
    for (int off = 1; off < 64; off <<= 1){
        unsigned int v = __shfl_up(cum, off);
        if (lane >= off) cum += v;
    }
    unsigned long long bal = __ballot(cum >= (unsigned)K_);
    int L = __ffsll(bal) - 1;
    unsigned int run = __shfl(cum, L) - __shfl(gs, L);
    int Bsel = 8*L + 7;
    {
        unsigned int c = run; bool fnd = false;
        #pragma unroll
        for (int t = 0; t < 8; ++t){
            unsigned int ht = __shfl(g[t], L, 64);
            if (!fnd && c + ht >= (unsigned)K_){ Bsel = 8*L + t; fnd = true; }
            c += ht;
        }
    }
    const float Tedge = __uint_as_float(0x3F800000u + ((unsigned)(Bsel + 1) << 15));
    const bool allin = (Bsel == 511);

    // count pass: this wave's survivor total (wave-uniform)
    unsigned int myc = 0;
    #pragma unroll
    for (int j = 0; j < 16; ++j){
        float f1 = __uint_as_float(fv[j]) + 1.0f;
        bool surv = (f1 < Tedge) || allin;
        myc += (unsigned int)__popcll(__ballot(surv));
    }
    if (lane == 0) cntW[p][ws] = myc;
    __syncthreads();

    // store pass: dense compaction at cross-wave base
    const unsigned long long mlt = (lane == 63) ? ~0ull >> 1 : (1ull << lane) - 1ull;
    unsigned int cnt = ws ? cntW[p][0] : 0u;
    #pragma unroll
    for (int j = 0; j < 16; ++j){
        float f1 = __uint_as_float(fv[j]) + 1.0f;
        bool surv = (f1 < Tedge) || allin;
        unsigned long long sb = __ballot(surv);
        unsigned int pos = cnt + (unsigned int)__popcll(sb & mlt);
        if (surv && pos < (unsigned)LISTCAP)
            lst[p][pos] = ((unsigned long long)fv[j] << 32) | (unsigned int)(j*128 + ws*64 + lane);
        cnt += (unsigned int)__popcll(sb);
    }
    __syncthreads();
    int m = (int)(cntW[p][0] + cntW[p][1]); if (m > LISTCAP) m = LISTCAP;

    // rank-select over both waves (keys unique: idx in low bits) -> exact top_k tie-break
    int* outp = idx_out + ((size_t)bN + q) * K_;
    for (int i = ws*64 + lane; i < m; i += 128){
        unsigned long long my = lst[p][i];
        int rank = 0;
        for (int jj = 0; jj < m; ++jj)
            rank += (lst[p][jj] < my) ? 1 : 0;
        if (rank < K_){
            int id = (int)(unsigned int)(my & 0xFFFFFFFFull);
            outp[rank] = id;
            kidx[p][rank] = id;
        }
    }
    __syncthreads();

    // fused h1 stats: ch = lane&31; (ws,half) quarters split the 32 neighbors (8 each)
    {
        const int ch = lane & 31;
        float w1a = W1[ch], w1b = W1[H_+ch], w1c = W1[2*H_+ch], b1c = b1[ch];
        float s = 0.f, qq = 0.f;
        #pragma unroll
        for (int r = 0; r < 8; ++r){
            int idr = kidx[p][ws*16 + half*8 + r];     // wave-uniform LDS broadcast
            float4 pn = xs4g[bN + idr];
            float rx = pn.x - qx, ry = pn.y - qy, rz = pn.z - qz;
            float h = fmaxf(fmaf(rx, w1a, fmaf(ry, w1b, fmaf(rz, w1c, b1c))), 0.0f);
            s += h; qq = fmaf(h, h, qq);
        }
        s  += __shfl_xor(s, 32, 64);
        qq += __shfl_xor(qq, 32, 64);
        if (lane < 32){
            int sh = (blockIdx.x & (NSH-1)) * 32 + ch;
            atomicAdd(&s1sh[sh], s);
            atomicAdd(&q1sh[sh], qq);
        }
    }

    // ---- h1 -> global in MFMA fragment layout; sub-wave ws emits sblk=ws (one uint4/lane) ----
    {
        const int id = kidx[p][lane & 31];
        float4 pn = xs4g[bN + id];
        float rx = pn.x - qx, ry = pn.y - qy, rz = pn.z - qz;
        uint4* dst = (uint4*)h1f + (size_t)(bN + q)*128 + ws*64 + lane;
        const int cb = ws*16 + half*8;
        const float4 wa0 = *(const float4*)(W1 + cb);
        const float4 wa1 = *(const float4*)(W1 + cb + 4);
        const float4 wb0 = *(const float4*)(W1 + H_ + cb);
        const float4 wb1 = *(const float4*)(W1 + H_ + cb + 4);
        const float4 wc0 = *(const float4*)(W1 + 2*H_ + cb);
        const float4 wc1 = *(const float4*)(W1 + 2*H_ + cb + 4);
        const float4 bv0 = *(const float4*)(b1 + cb);
        const float4 bv1 = *(const float4*)(b1 + cb + 4);
        float h0 = fmaxf(fmaf(rx, wa0.x, fmaf(ry, wb0.x, fmaf(rz, wc0.x, bv0.x))), 0.0f);
        float h1v= fmaxf(fmaf(rx, wa0.y, fmaf(ry, wb0.y, fmaf(rz, wc0.y, bv0.y))), 0.0f);
        float h2v= fmaxf(fmaf(rx, wa0.z, fmaf(ry, wb0.z, fmaf(rz, wc0.z, bv0.z))), 0.0f);
        float h3 = fmaxf(fmaf(rx, wa0.w, fmaf(ry, wb0.w, fmaf(rz, wc0.w, bv0.w))), 0.0f);
        float h4 = fmaxf(fmaf(rx, wa1.x, fmaf(ry, wb1.x, fmaf(rz, wc1.x, bv1.x))), 0.0f);
        float h5 = fmaxf(fmaf(rx, wa1.y, fmaf(ry, wb1.y, fmaf(rz, wc1.y, bv1.y))), 0.0f);
        float h6 = fmaxf(fmaf(rx, wa1.z, fmaf(ry, wb1.z, fmaf(rz, wc1.z, bv1.z))), 0.0f);
        float h7 = fmaxf(fmaf(rx, wa1.w, fmaf(ry, wb1.w, fmaf(rz, wc1.w, bv1.w))), 0.0f);
        uint4 o;
        o.x = pk2(h0, h1v); o.y = pk2(h2v, h3); o.z = pk2(h4, h5); o.w = pk2(h6, h7);
        *dst = o;
    }
}

// ---- shared head: BN1 scale/shift + W2f frags + b2p into LDS (bit-identical to old k_prep2) ----
__device__ __forceinline__ void build_l2(const float* __restrict__ s1s, const float* __restrict__ q1s,
                                         const float* __restrict__ g1, const float* __restrict__ be1,
                                         const float* __restrict__ W2, const float* __restrict__ b2,
                                         float* a1L, float* bb1L, unsigned int* W2L, float* b2pL,
                                         int tid){
    if (tid < H_){
        float s = shsum(s1s, tid), qq = shsum(q1s, tid);
        float mm = s*INVR_, vv = qq*INVR_ - mm*mm;
        float aa = g1[tid] / sqrtf(vv + EPS_);
        a1L[tid]  = aa;
        bb1L[tid] = fmaf(-aa, mm, be1[tid]);
    }
    __syncthreads();
    #pragma unroll
    for (int e = 0; e < 2; ++e){
        int d = tid*2 + e;
        int jj = d & 3, ln = (d >> 2) & 63, s = d >> 8;
        int col = ln & 31;
        int k0 = s*16 + ((ln >> 5) << 3) + 2*jj;
        W2L[d] = pk2(a1L[k0]*W2[k0*H_ + col], a1L[k0+1]*W2[(k0+1)*H_ + col]);
    }
    if (tid < H_){
        float acc = b2[tid];
        #pragma unroll 4
        for (int h = 0; h < H_; ++h) acc = fmaf(bb1L[h], W2[h*H_ + tid], acc);
        b2pL[tid] = acc;
    }
}

// ---- k_h2stats (+fused prep2): h1-frags -> layer2 MFMA -> relu -> per-channel stats ----
__global__ __launch_bounds__(256,4) void k_h2stats(const uint4* __restrict__ h1f,
                                                   const float* __restrict__ s1s, const float* __restrict__ q1s,
                                                   const float* __restrict__ g1, const float* __restrict__ be1,
                                                   const float* __restrict__ W2, const float* __restrict__ b2,
                                                   float* gsum, float* gsq){
    __shared__ float redS[H_], redQ[H_];
    __shared__ float a1L[H_], bb1L[H_], b2pL[H_];
    __shared__ unsigned int W2L[512];
    const int tid = threadIdx.x, lane = tid & 63, w = tid >> 6;
    const int m = lane & 31;
    if (tid < H_){ redS[tid] = 0.f; redQ[tid] = 0.f; }
    build_l2(s1s, q1s, g1, be1, W2, b2, a1L, bb1L, W2L, b2pL, tid);
    __syncthreads();

    union { uint4 u4; f16x8 v; } Bf0, Bf1;
    Bf0.u4 = ((const uint4*)W2L)[lane];
    Bf1.u4 = ((const uint4*)W2L)[64 + lane];
    float b2c = b2pL[m];
    const int blk0 = blockIdx.x*16 + w*4;

    float s = 0.f, q = 0.f;
    #pragma unroll
    for (int t = 0; t < 4; ++t){
        union { uint4 u4; f16x8 v; } a0, a1f;
        a0.u4  = h1f[(size_t)(blk0 + t)*128 + lane];
        a1f.u4 = h1f[(size_t)(blk0 + t)*128 + 64 + lane];
        f32x16 acc;
        #pragma unroll
        for (int i = 0; i < 16; ++i) acc[i] = b2c;
        acc = __builtin_amdgcn_mfma_f32_32x32x16_f16(a0.v,  Bf0.v, acc, 0, 0, 0);
        acc = __builtin_amdgcn_mfma_f32_32x32x16_f16(a1f.v, Bf1.v, acc, 0, 0, 0);
        #pragma unroll
        for (int i = 0; i < 16; ++i){
            float v = fmaxf(acc[i], 0.0f);
            s += v; q = fmaf(v, v, q);
        }
    }
    s += __shfl_xor(s, 32, 64);
    q += __shfl_xor(q, 32, 64);
    if (lane < 32){ atomicAdd(&redS[m], s); atomicAdd(&redQ[m], q); }
    __syncthreads();
    if (tid < H_){ atomicAdd(&gsum[tid], redS[tid]); atomicAdd(&gsq[tid], redQ[tid]); }
}

// ---- k_out (+fused prep2+prep3): builds W2f/b2p AND W3f in-block, then the fused 2-layer MFMA ----
#define PHASEA(T, H2P, GSEL) do { \
    union { uint4 u4; f16x8 v; } B0f, B1f; \
    B0f.u4 = h1f[(size_t)(blk0 + (T))*128 + lane]; \
    B1f.u4 = h1f[(size_t)(blk0 + (T))*128 + 64 + lane]; \
    int row = rB + (T)*32 + m; \
    int bb_ = row >> 16; \
    int idr = idx[row]; \
    const uint4* gpp = (const uint4*)(pf16 + ((size_t)bb_*N_ + idr)*8); \
    uint4 ga = gpp[0], gb = gpp[1]; \
    GSEL[0] = half ? gb.x : ga.x; \
    GSEL[1] = half ? gb.y : ga.y; \
    GSEL[2] = half ? gb.z : ga.z; \
    GSEL[3] = half ? gb.w : ga.w; \
    f32x16 c2; \
    _Pragma("unroll") \
    for (int i = 0; i < 16; ++i) c2[i] = b2v[i]; \
    c2 = __builtin_amdgcn_mfma_f32_32x32x16_f16(A0.v, B0f.v, c2, 0, 0, 0); \
    c2 = __builtin_amdgcn_mfma_f32_32x32x16_f16(A1.v, B1f.v, c2, 0, 0, 0); \
    _Pragma("unroll") \
    for (int p = 0; p < 8; ++p){ \
        float v0 = fmaxf(c2[2*p],   0.0f); \
        float v1 = fmaxf(c2[2*p+1], 0.0f); \
        unsigned int ow = pk2(v0, v1); \
        unsigned int ot = __shfl_xor(ow, 32, 64); \
        int a = p >> 1, bb = p & 1; \
        H2P[4*a + bb]     = half ? ot : ow; \
        H2P[4*a + 2 + bb] = half ? ow : ot; \
    } \
} while(0)

#define REDST(ACC, T) do { \
    float v = ACC[0]; \
    _Pragma("unroll") \
    for (int i = 1; i < 16; ++i) v = fmaxf(v, ACC[i]); \
    v = fmaxf(v, __shfl_xor(v, 32, 64)); \
    if (lane < 32){ \
        int g = blk0 + (T); \
        out_pre[(size_t)g*COUT_ + m] = v; \
        atomicAdd(&redS[m], v); \
        atomicAdd(&redQ[m], v*v); \
    } \
} while(0)

__global__ __launch_bounds__(256,4) void k_out(const uint4* __restrict__ h1f, const int* __restrict__ idx,
                                               const float* __restrict__ s1s, const float* __restrict__ q1s,
                                               const float* __restrict__ g1, const float* __restrict__ be1,
                                               const float* __restrict__ W2, const float* __restrict__ b2,
                                               const float* __restrict__ s2, const float* __restrict__ q2,
                                               const float* __restrict__ g2, const float* __restrict__ be2,
                                               const float* __restrict__ W3, const float* __restrict__ b3,
                                               const unsigned int* __restrict__ pf16,
                                               float* __restrict__ out_pre, float* gsum, float* gsq){
    __shared__ uint4 Wls[2112];                      // 33 KB: W3f fragments (built in-block)
    __shared__ float redS[COUT_], redQ[COUT_];
    __shared__ float a1L[H_], bb1L[H_], b2pL[H_], aa2L[H_], bb2L[H_];
    __shared__ unsigned int W2L[512];
    const int tid = threadIdx.x, lane = tid & 63, w = tid >> 6;
    const int half = lane >> 5, m = lane & 31;
    if (tid < COUT_){
        redS[tid] = 0.f; redQ[tid] = 0.f;
        float mm = s2[tid]*INVR_, vv = q2[tid]*INVR_ - mm*mm;
        float aa = g2[tid] / sqrtf(vv + EPS_);
        aa2L[tid] = aa;
        bb2L[tid] = fmaf(-aa, mm, be2[tid]);
    }
    build_l2(s1s, q1s, g1, be1, W2, b2, a1L, bb1L, W2L, b2pL, tid);
    {   // W3f -> Wls (identical dword mapping + arithmetic to old k_prep3)
        int jj = tid & 3, ln = tid >> 2;
        int col = ln & 31, c0 = ((ln >> 5) << 3) + 2*jj;
        unsigned int* WlsD = (unsigned int*)Wls;
        #pragma unroll 4
        for (int i = 0; i < 32; ++i){
            float a = aa2L[i];
            WlsD[i*256 + tid] = pk2(a*W3[i*512 + c0*COUT_ + col], a*W3[i*512 + (c0+1)*COUT_ + col]);
        }
        float v0 = b3[c0*COUT_ + col], v1 = b3[(c0+1)*COUT_ + col];
        #pragma unroll 4
        for (int h = 0; h < H_; ++h){
            v0 = fmaf(bb2L[h], W3[h*512 + c0*COUT_ + col], v0);
            v1 = fmaf(bb2L[h], W3[h*512 + (c0+1)*COUT_ + col], v1);
        }
        WlsD[32*256 + tid] = pk2(v0, v1);
    }
    __syncthreads();

    const int rB = blockIdx.x*256 + w*64;
    const int blk0 = blockIdx.x*8 + w*2;

    union { uint4 u4; f16x8 v; } A0, A1;     // W2'^T A-frags
    A0.u4 = ((const uint4*)W2L)[lane];
    A1.u4 = ((const uint4*)W2L)[64 + lane];
    float b2v[16];
    #pragma unroll
    for (int i = 0; i < 16; ++i) b2v[i] = b2pL[(i&3) + 8*(i>>2) + 4*half];

    unsigned int h2p0[16], h2p1[16];
    unsigned int gsel0[4], gsel1[4];
    PHASEA(0, h2p0, gsel0);
    PHASEA(1, h2p1, gsel1);

    f32x16 acc0, acc1;
    #pragma unroll
    for (int i = 0; i < 16; ++i){ acc0[i] = 0.f; acc1[i] = 0.f; }
    #pragma unroll
    for (int kb = 0; kb < 32; ++kb){
        union { uint4 u4; f16x8 v; } bf; bf.u4 = Wls[kb*64 + lane];   // read ONCE, feeds both t
        const unsigned int sel = (kb & 1) ? 0x03020302u : 0x01000100u;
        unsigned int hr0 = h2p0[kb >> 1];
        unsigned int hd0 = __builtin_amdgcn_perm(hr0, hr0, sel);
        union { unsigned int u[4]; f16x8 v; } af;
        #pragma unroll
        for (int jj = 0; jj < 4; ++jj) af.u[jj] = pkmul(hd0, gsel0[jj]);
        acc0 = __builtin_amdgcn_mfma_f32_32x32x16_f16(af.v, bf.v, acc0, 0, 0, 0);
        unsigned int hr1 = h2p1[kb >> 1];
        unsigned int hd1 = __builtin_amdgcn_perm(hr1, hr1, sel);
        #pragma unroll
        for (int jj = 0; jj < 4; ++jj) af.u[jj] = pkmul(hd1, gsel1[jj]);
        acc1 = __builtin_amdgcn_mfma_f32_32x32x16_f16(af.v, bf.v, acc1, 0, 0, 0);
    }
    {   // bias step: A = gp, B = b3'
        union { uint4 u4; f16x8 v; } bf; bf.u4 = Wls[32*64 + lane];
        union { unsigned int u[4]; f16x8 v; } af;
        #pragma unroll
        for (int jj = 0; jj < 4; ++jj) af.u[jj] = gsel0[jj];
        acc0 = __builtin_amdgcn_mfma_f32_32x32x16_f16(af.v, bf.v, acc0, 0, 0, 0);
        #pragma unroll
        for (int jj = 0; jj < 4; ++jj) af.u[jj] = gsel1[jj];
        acc1 = __builtin_amdgcn_mfma_f32_32x32x16_f16(af.v, bf.v, acc1, 0, 0, 0);
    }

    REDST(acc0, 0);
    REDST(acc1, 1);

    __syncthreads();
    if (tid < COUT_){ atomicAdd(&gsum[tid], redS[tid]); atomicAdd(&gsq[tid], redQ[tid]); }
}

// ---- k_bn: vectorized float4 ----
__global__ __launch_bounds__(256) void k_bn(const float4* __restrict__ out_pre4,
                                            const float* __restrict__ s3, const float* __restrict__ q3,
                                            const float* __restrict__ gbn, const float* __restrict__ bbn,
                                            float4* __restrict__ out4){
    int i = blockIdx.x*256 + threadIdx.x;          // 65536 float4s
    int o = (i*4) & (COUT_-1);
    float4 v = out_pre4[i];
    float4 r;
    {
        float mm = s3[o]*INVBN_;   float vv = q3[o]*INVBN_   - mm*mm;
        float aa = gbn[o]/sqrtf(vv+EPS_);   r.x = fmaf(aa, v.x, fmaf(-aa, mm, bbn[o]));
    }
    {
        float mm = s3[o+1]*INVBN_; float vv = q3[o+1]*INVBN_ - mm*mm;
        float aa = gbn[o+1]/sqrtf(vv+EPS_); r.y = fmaf(aa, v.y, fmaf(-aa, mm, bbn[o+1]));
    }
    {
        float mm = s3[o+2]*INVBN_; float vv = q3[o+2]*INVBN_ - mm*mm;
        float aa = gbn[o+2]/sqrtf(vv+EPS_); r.z = fmaf(aa, v.z, fmaf(-aa, mm, bbn[o+2]));
    }
    {
        float mm = s3[o+3]*INVBN_; float vv = q3[o+3]*INVBN_ - mm*mm;
        float aa = gbn[o+3]/sqrtf(vv+EPS_); r.w = fmaf(aa, v.w, fmaf(-aa, mm, bbn[o+3]));
    }
    out4[i] = r;
}

extern "C" void kernel_launch(void* const* d_in, const int* in_sizes, int n_in,
                              void* d_out, int out_size, void* d_ws, size_t ws_size,
                              hipStream_t stream){
    const float* xyz    = (const float*)d_in[0];
    const float* points = (const float*)d_in[1];
    const float* W1  = (const float*)d_in[2];
    const float* b1  = (const float*)d_in[3];
    const float* g1  = (const float*)d_in[4];
    const float* be1 = (const float*)d_in[5];
    const float* W2  = (const float*)d_in[6];
    const float* b2  = (const float*)d_in[7];
    const float* g2  = (const float*)d_in[8];
    const float* be2 = (const float*)d_in[9];
    const float* W3  = (const float*)d_in[10];
    const float* b3  = (const float*)d_in[11];
    const float* gbn = (const float*)d_in[12];
    const float* bbn = (const float*)d_in[13];
    float* out = (float*)d_out;

    // ws layout (bytes)
    char* base = (char*)d_ws;
    int*            idx     = (int*)(base + 0);                     // 1,048,576
    float*          out_pre = (float*)(base + 1048576);             // 1,048,576
    unsigned int*   pf16    = (unsigned int*)(base + 2097152);      //    262,144
    float*          st      = (float*)(base + 2395264);             //      5,120 (1280 floats)
    float4*         xs4g    = (float4*)(base + 2400384);            //    131,072
    unsigned int*   h1f     = (unsigned int*)(base + 4194304);      // 16,777,216 (R_*H_*2B, frag layout)
    // st floats: s1s[512] | q1s[512] | s2[32] | q2[32] | s3[32] | q3[32]
    float *s1s=st, *q1s=st+512, *s2=st+1024, *q2=st+1056, *s3=st+1088, *q3=st+1120;

    hipLaunchKernelGGL(k_prep0,   dim3(288),      dim3(256), 0, stream, xyz, points, xs4g, pf16, st);
    hipLaunchKernelGGL(k_knn,     dim3(B_*N_/2),  dim3(256), 0, stream, xs4g, W1, b1, idx, s1s, q1s, h1f);
    hipLaunchKernelGGL(k_h2stats, dim3(R_/512),   dim3(256), 0, stream, (const uint4*)h1f,
                       s1s, q1s, g1, be1, W2, b2, s2, q2);
    hipLaunchKernelGGL(k_out,     dim3(R_/256),   dim3(256), 0, stream, (const uint4*)h1f, idx,
                       s1s, q1s, g1, be1, W2, b2, s2, q2, g2, be2, W3, b3, pf16, out_pre, s3, q3);
    hipLaunchKernelGGL(k_bn,      dim3(256),      dim3(256), 0, stream, (const float4*)out_pre, s3, q3,
                       gbn, bbn, (float4*)out);
}

// Round 10
// 161.116 us; speedup vs baseline: 1.0832x; 1.0832x over previous
//
#include <hip/hip_runtime.h>

#define B_ 4
#define N_ 2048
#define K_ 32
#define CIN_ 16
#define COUT_ 32
#define H_ 32
#define R_ (B_*N_*K_)      // 262144 rows through the weight-net
#define EPS_ 1e-5f
#define INVR_ (1.0f/(float)R_)
#define INVBN_ (1.0f/(float)(B_*N_))
#define LISTCAP 160
#define NSH 16             // stat shadows (applied to ALL cross-block stat reductions)

typedef __attribute__((ext_vector_type(8)))  _Float16 f16x8;
typedef __attribute__((ext_vector_type(2)))  __fp16   hw16x2;   // builtin cvt_pkrtz return type
typedef __attribute__((ext_vector_type(2)))  _Float16 f16x2;
typedef __attribute__((ext_vector_type(16))) float    f32x16;

__device__ __forceinline__ float dot3f(float ax,float ay,float az,float bx,float by,float bz){
    return fmaf(az,bz, fmaf(ay,by, ax*bx));
}
__device__ __forceinline__ unsigned int pk2(float a, float b){   // packed f16 pair (RTZ)
    union { hw16x2 v; unsigned int u; } c;
    c.v = __builtin_amdgcn_cvt_pkrtz(a, b);
    return c.u;
}
__device__ __forceinline__ unsigned int pkmul(unsigned int a, unsigned int b){  // v_pk_mul_f16
    union { unsigned int u; f16x2 v; } x, y, r;
    x.u = a; y.u = b; r.v = x.v * y.v; return r.u;
}
// sum of NSH shadow accumulators
__device__ __forceinline__ float shsum(const float* __restrict__ p, int k){
    float s = 0.f;
    #pragma unroll
    for (int i = 0; i < NSH; ++i) s += p[i*32 + k];
    return s;
}

// ---- prep0: xs4g[b*N+n] = (x,y,z,|p|^2); pf16 = f16-packed points; zero stats ----
__global__ __launch_bounds__(256) void k_prep0(const float* __restrict__ xyz, const float* __restrict__ points,
                                               float4* __restrict__ xs4g, unsigned int* __restrict__ pf16,
                                               float* __restrict__ st){
    int flat = blockIdx.x*256 + threadIdx.x;      // 288 blocks x 256 = 73728 = 8192 + 65536
    if (flat < 8192){
        float x = xyz[3*flat], y = xyz[3*flat+1], z = xyz[3*flat+2];
        xs4g[flat] = make_float4(x, y, z, dot3f(x,y,z,x,y,z));
    } else {
        int p = flat - 8192;
        pf16[p] = pk2(points[2*p], points[2*p+1]);
    }
    if (blockIdx.x == 0){
        for (int j = threadIdx.x; j < 3072; j += 256) st[j] = 0.f;   // 6 stat arrays x 512 shadows
    }
}

// ---------------- KNN: 1 wave/query, wave-autonomous (R5 proven-best variant, reverted) ----------------
// (256,5): VGPR cap ~96 -> fv[32] cache fits (LLVM AGPR-spills cleanly, zero scratch). 4 experiments
// (spill/no-spill x occ 43-62% x chain 32/16) all land 43-49us -> stop tuning; this is the floor form.
__global__ __launch_bounds__(256,5) void k_knn(const float4* __restrict__ xs4g,
                                               const float* __restrict__ W1, const float* __restrict__ b1,
                                               int* __restrict__ idx_out,
                                               float* __restrict__ s1sh, float* __restrict__ q1sh,
                                               unsigned int* __restrict__ h1f){
    __shared__ unsigned int hist[4][512][2];          // 16 KB: per-wave 512 buckets x2 replicas
    __shared__ unsigned long long lst[4][LISTCAP];    // 5 KB
    __shared__ int kidx[4][K_];                       // 0.5 KB

    const int tid  = threadIdx.x;
    const int w    = tid >> 6;
    const int lane = tid & 63;
    const int half = lane >> 5;
    const int b    = blockIdx.x >> 9;
    const int q    = ((blockIdx.x & 511) << 2) + w;
    const int bN   = b * N_;
    unsigned int* hw = &hist[w][0][0];

    const uint4 z4 = make_uint4(0,0,0,0);
    uint4* h4 = (uint4*)hw;                           // 256 uint4 per wave
    #pragma unroll
    for (int i = 0; i < 4; ++i) h4[i*64 + lane] = z4;

    const float4 qp = xs4g[bN + q];
    const float qx = qp.x, qy = qp.y, qz = qp.z, sqq = qp.w;

    // pass 1: 32 candidates/lane, cache d-bits, linear histogram
    unsigned int fv[32];
    #pragma unroll
    for (int j = 0; j < 32; ++j){
        int c = j*64 + lane;
        float4 pt = xs4g[bN + c];
        float d = fmaf(-2.0f, dot3f(qx,qy,qz, pt.x,pt.y,pt.z), sqq) + pt.w;
        fv[j] = __float_as_uint(d);
        unsigned int u1 = __float_as_uint(d + 1.0f);
        unsigned int key = (u1 <= 0x3F800000u) ? 0u : ((u1 - 0x3F800000u) >> 15);
        key = key > 511u ? 511u : key;
        atomicAdd(&hw[key*2 + (lane & 1)], 1u);
    }

    // select: smallest bucket with cumulative >= K (lane covers 8 buckets)
    unsigned int g[8];
    #pragma unroll
    for (int t = 0; t < 4; ++t){
        uint4 h = ((const uint4*)hw)[lane*4 + t];
        g[2*t]   = h.x + h.y;
        g[2*t+1] = h.z + h.w;
    }
    unsigned int gs = 0;
    #pragma unroll
    for (int t = 0; t < 8; ++t) gs += g[t];
    unsigned int cum = gs;
    #pragma unroll
    for (int off = 1; off < 64; off <<= 1){
        unsigned int v = __shfl_up(cum, off);
        if (lane >= off) cum += v;
    }
    unsigned long long bal = __ballot(cum >= (unsigned)K_);
    int L = __ffsll(bal) - 1;
    unsigned int run = __shfl(cum, L) - __shfl(gs, L);
    int Bsel = 8*L + 7;
    {
        unsigned int c = run; bool fnd = false;
        #pragma unroll
        for (int t = 0; t < 8; ++t){
            unsigned int ht = __shfl(g[t], L, 64);
            if (!fnd && c + ht >= (unsigned)K_){ Bsel = 8*L + t; fnd = true; }
            c += ht;
        }
    }
    const float Tedge = __uint_as_float(0x3F800000u + ((unsigned)(Bsel + 1) << 15));
    const bool allin = (Bsel == 511);

    // pass 2: ballot-compaction of survivors (f1 < Tedge <=> bucket <= Bsel)
    const unsigned long long mlt = (lane == 63) ? ~0ull >> 1 : (1ull << lane) - 1ull;
    unsigned int cnt = 0;
    #pragma unroll
    for (int j = 0; j < 32; ++j){
        float f1 = __uint_as_float(fv[j]) + 1.0f;
        bool surv = (f1 < Tedge) || allin;
        unsigned long long sb = __ballot(surv);
        unsigned int pos = cnt + (unsigned int)__popcll(sb & mlt);
        if (surv && pos < (unsigned)LISTCAP)
            lst[w][pos] = ((unsigned long long)fv[j] << 32) | (unsigned int)(j*64 + lane);
        cnt += (unsigned int)__popcll(sb);
    }
    int m = (int)cnt; if (m > LISTCAP) m = LISTCAP;

    // rank-select (keys unique: idx in low bits) -> exact top_k tie-break
    int* outp = idx_out + ((size_t)bN + q) * K_;
    for (int i = lane; i < m; i += 64){
        unsigned long long my = lst[w][i];
        int rank = 0;
        for (int jj = 0; jj < m; ++jj)
            rank += (lst[w][jj] < my) ? 1 : 0;
        if (rank < K_){
            int id = (int)(unsigned int)(my & 0xFFFFFFFFull);
            outp[rank] = id;
            kidx[w][rank] = id;
        }
    }

    // fused h1 stats: ch = lane&31; halves split the 32 neighbors (16 each)
    {
        const int ch = lane & 31;
        float w1a = W1[ch], w1b = W1[H_+ch], w1c = W1[2*H_+ch], b1c = b1[ch];
        float s = 0.f, qq = 0.f;
        #pragma unroll
        for (int r = 0; r < 16; ++r){
            int idr = kidx[w][half*16 + r];            // wave-uniform LDS broadcast
            float4 pn = xs4g[bN + idr];
            float rx = pn.x - qx, ry = pn.y - qy, rz = pn.z - qz;
            float h = fmaxf(fmaf(rx, w1a, fmaf(ry, w1b, fmaf(rz, w1c, b1c))), 0.0f);
            s += h; qq = fmaf(h, h, qq);
        }
        s  += __shfl_xor(s, 32, 64);
        qq += __shfl_xor(qq, 32, 64);
        if (lane < 32){
            int sh = (blockIdx.x & (NSH-1)) * 32 + ch;
            atomicAdd(&s1sh[sh], s);
            atomicAdd(&q1sh[sh], qq);
        }
    }

    // ---- h1 -> global in MFMA fragment layout: lane = (row lane&31, ch-block (lane>>5)*8) ----
    {
        const int id = kidx[w][lane & 31];
        float4 pn = xs4g[bN + id];
        float rx = pn.x - qx, ry = pn.y - qy, rz = pn.z - qz;
        uint4* dst = (uint4*)h1f + (size_t)(bN + q)*128 + lane;
        const int c0 = half*8;
        #pragma unroll
        for (int sblk = 0; sblk < 2; ++sblk){
            const int cb = sblk*16 + c0;
            const float4 wa0 = *(const float4*)(W1 + cb);
            const float4 wa1 = *(const float4*)(W1 + cb + 4);
            const float4 wb0 = *(const float4*)(W1 + H_ + cb);
            const float4 wb1 = *(const float4*)(W1 + H_ + cb + 4);
            const float4 wc0 = *(const float4*)(W1 + 2*H_ + cb);
            const float4 wc1 = *(const float4*)(W1 + 2*H_ + cb + 4);
            const float4 bv0 = *(const float4*)(b1 + cb);
            const float4 bv1 = *(const float4*)(b1 + cb + 4);
            float h0 = fmaxf(fmaf(rx, wa0.x, fmaf(ry, wb0.x, fmaf(rz, wc0.x, bv0.x))), 0.0f);
            float h1v= fmaxf(fmaf(rx, wa0.y, fmaf(ry, wb0.y, fmaf(rz, wc0.y, bv0.y))), 0.0f);
            float h2v= fmaxf(fmaf(rx, wa0.z, fmaf(ry, wb0.z, fmaf(rz, wc0.z, bv0.z))), 0.0f);
            float h3 = fmaxf(fmaf(rx, wa0.w, fmaf(ry, wb0.w, fmaf(rz, wc0.w, bv0.w))), 0.0f);
            float h4 = fmaxf(fmaf(rx, wa1.x, fmaf(ry, wb1.x, fmaf(rz, wc1.x, bv1.x))), 0.0f);
            float h5 = fmaxf(fmaf(rx, wa1.y, fmaf(ry, wb1.y, fmaf(rz, wc1.y, bv1.y))), 0.0f);
            float h6 = fmaxf(fmaf(rx, wa1.z, fmaf(ry, wb1.z, fmaf(rz, wc1.z, bv1.z))), 0.0f);
            float h7 = fmaxf(fmaf(rx, wa1.w, fmaf(ry, wb1.w, fmaf(rz, wc1.w, bv1.w))), 0.0f);
            uint4 o;
            o.x = pk2(h0, h1v); o.y = pk2(h2v, h3); o.z = pk2(h4, h5); o.w = pk2(h6, h7);
            dst[sblk*64] = o;
        }
    }
}

// ---- shared head: BN1 scale/shift + W2f frags + b2p into LDS (bit-identical to old k_prep2) ----
__device__ __forceinline__ void build_l2(const float* __restrict__ s1s, const float* __restrict__ q1s,
                                         const float* __restrict__ g1, const float* __restrict__ be1,
                                         const float* __restrict__ W2, const float* __restrict__ b2,
                                         float* a1L, float* bb1L, unsigned int* W2L, float* b2pL,
                                         int tid){
    if (tid < H_){
        float s = shsum(s1s, tid), qq = shsum(q1s, tid);
        float mm = s*INVR_, vv = qq*INVR_ - mm*mm;
        float aa = g1[tid] / sqrtf(vv + EPS_);
        a1L[tid]  = aa;
        bb1L[tid] = fmaf(-aa, mm, be1[tid]);
    }
    __syncthreads();
    #pragma unroll
    for (int e = 0; e < 2; ++e){
        int d = tid*2 + e;
        int jj = d & 3, ln = (d >> 2) & 63, s = d >> 8;
        int col = ln & 31;
        int k0 = s*16 + ((ln >> 5) << 3) + 2*jj;
        W2L[d] = pk2(a1L[k0]*W2[k0*H_ + col], a1L[k0+1]*W2[(k0+1)*H_ + col]);
    }
    if (tid < H_){
        float acc = b2[tid];
        #pragma unroll 4
        for (int h = 0; h < H_; ++h) acc = fmaf(bb1L[h], W2[h*H_ + tid], acc);
        b2pL[tid] = acc;
    }
}

// ---- k_h2stats (+fused prep2): h1-frags -> layer2 MFMA -> relu -> per-channel stats ----
// Tail atomics now SHADOWED (16 copies): was 512 blocks RMW-serializing on 64 addresses.
__global__ __launch_bounds__(256,4) void k_h2stats(const uint4* __restrict__ h1f,
                                                   const float* __restrict__ s1s, const float* __restrict__ q1s,
                                                   const float* __restrict__ g1, const float* __restrict__ be1,
                                                   const float* __restrict__ W2, const float* __restrict__ b2,
                                                   float* s2s, float* q2s){
    __shared__ float redS[H_], redQ[H_];
    __shared__ float a1L[H_], bb1L[H_], b2pL[H_];
    __shared__ unsigned int W2L[512];
    const int tid = threadIdx.x, lane = tid & 63, w = tid >> 6;
    const int m = lane & 31;
    if (tid < H_){ redS[tid] = 0.f; redQ[tid] = 0.f; }
    build_l2(s1s, q1s, g1, be1, W2, b2, a1L, bb1L, W2L, b2pL, tid);
    __syncthreads();

    union { uint4 u4; f16x8 v; } Bf0, Bf1;
    Bf0.u4 = ((const uint4*)W2L)[lane];
    Bf1.u4 = ((const uint4*)W2L)[64 + lane];
    float b2c = b2pL[m];
    const int blk0 = blockIdx.x*16 + w*4;

    float s = 0.f, q = 0.f;
    #pragma unroll
    for (int t = 0; t < 4; ++t){
        union { uint4 u4; f16x8 v; } a0, a1f;
        a0.u4  = h1f[(size_t)(blk0 + t)*128 + lane];
        a1f.u4 = h1f[(size_t)(blk0 + t)*128 + 64 + lane];
        f32x16 acc;
        #pragma unroll
        for (int i = 0; i < 16; ++i) acc[i] = b2c;
        acc = __builtin_amdgcn_mfma_f32_32x32x16_f16(a0.v,  Bf0.v, acc, 0, 0, 0);
        acc = __builtin_amdgcn_mfma_f32_32x32x16_f16(a1f.v, Bf1.v, acc, 0, 0, 0);
        #pragma unroll
        for (int i = 0; i < 16; ++i){
            float v = fmaxf(acc[i], 0.0f);
            s += v; q = fmaf(v, v, q);
        }
    }
    s += __shfl_xor(s, 32, 64);
    q += __shfl_xor(q, 32, 64);
    if (lane < 32){ atomicAdd(&redS[m], s); atomicAdd(&redQ[m], q); }
    __syncthreads();
    if (tid < H_){
        int sh = (blockIdx.x & (NSH-1)) * 32 + tid;
        atomicAdd(&s2s[sh], redS[tid]);
        atomicAdd(&q2s[sh], redQ[tid]);
    }
}

// ---- k_out (+fused prep2+prep3): builds W2f/b2p AND W3f in-block, then the fused 2-layer MFMA ----
#define PHASEA(T, H2P, GSEL) do { \
    union { uint4 u4; f16x8 v; } B0f, B1f; \
    B0f.u4 = h1f[(size_t)(blk0 + (T))*128 + lane]; \
    B1f.u4 = h1f[(size_t)(blk0 + (T))*128 + 64 + lane]; \
    int row = rB + (T)*32 + m; \
    int bb_ = row >> 16; \
    int idr = idx[row]; \
    const uint4* gpp = (const uint4*)(pf16 + ((size_t)bb_*N_ + idr)*8); \
    uint4 ga = gpp[0], gb = gpp[1]; \
    GSEL[0] = half ? gb.x : ga.x; \
    GSEL[1] = half ? gb.y : ga.y; \
    GSEL[2] = half ? gb.z : ga.z; \
    GSEL[3] = half ? gb.w : ga.w; \
    f32x16 c2; \
    _Pragma("unroll") \
    for (int i = 0; i < 16; ++i) c2[i] = b2v[i]; \
    c2 = __builtin_amdgcn_mfma_f32_32x32x16_f16(A0.v, B0f.v, c2, 0, 0, 0); \
    c2 = __builtin_amdgcn_mfma_f32_32x32x16_f16(A1.v, B1f.v, c2, 0, 0, 0); \
    _Pragma("unroll") \
    for (int p = 0; p < 8; ++p){ \
        float v0 = fmaxf(c2[2*p],   0.0f); \
        float v1 = fmaxf(c2[2*p+1], 0.0f); \
        unsigned int ow = pk2(v0, v1); \
        unsigned int ot = __shfl_xor(ow, 32, 64); \
        int a = p >> 1, bb = p & 1; \
        H2P[4*a + bb]     = half ? ot : ow; \
        H2P[4*a + 2 + bb] = half ? ow : ot; \
    } \
} while(0)

#define REDST(ACC, T) do { \
    float v = ACC[0]; \
    _Pragma("unroll") \
    for (int i = 1; i < 16; ++i) v = fmaxf(v, ACC[i]); \
    v = fmaxf(v, __shfl_xor(v, 32, 64)); \
    if (lane < 32){ \
        int g = blk0 + (T); \
        out_pre[(size_t)g*COUT_ + m] = v; \
        atomicAdd(&redS[m], v); \
        atomicAdd(&redQ[m], v*v); \
    } \
} while(0)

__global__ __launch_bounds__(256,4) void k_out(const uint4* __restrict__ h1f, const int* __restrict__ idx,
                                               const float* __restrict__ s1s, const float* __restrict__ q1s,
                                               const float* __restrict__ g1, const float* __restrict__ be1,
                                               const float* __restrict__ W2, const float* __restrict__ b2,
                                               const float* __restrict__ s2s, const float* __restrict__ q2s,
                                               const float* __restrict__ g2, const float* __restrict__ be2,
                                               const float* __restrict__ W3, const float* __restrict__ b3,
                                               const unsigned int* __restrict__ pf16,
                                               float* __restrict__ out_pre, float* s3s, float* q3s){
    __shared__ uint4 Wls[2112];                      // 33 KB: W3f fragments (built in-block)
    __shared__ float redS[COUT_], redQ[COUT_];
    __shared__ float a1L[H_], bb1L[H_], b2pL[H_], aa2L[H_], bb2L[H_];
    __shared__ unsigned int W2L[512];
    const int tid = threadIdx.x, lane = tid & 63, w = tid >> 6;
    const int half = lane >> 5, m = lane & 31;
    if (tid < COUT_){
        redS[tid] = 0.f; redQ[tid] = 0.f;
        float ss = shsum(s2s, tid), qq = shsum(q2s, tid);   // shadow-summed s2/q2
        float mm = ss*INVR_, vv = qq*INVR_ - mm*mm;
        float aa = g2[tid] / sqrtf(vv + EPS_);
        aa2L[tid] = aa;
        bb2L[tid] = fmaf(-aa, mm, be2[tid]);
    }
    build_l2(s1s, q1s, g1, be1, W2, b2, a1L, bb1L, W2L, b2pL, tid);
    {   // W3f -> Wls (identical dword mapping + arithmetic to old k_prep3)
        int jj = tid & 3, ln = tid >> 2;
        int col = ln & 31, c0 = ((ln >> 5) << 3) + 2*jj;
        unsigned int* WlsD = (unsigned int*)Wls;
        #pragma unroll 4
        for (int i = 0; i < 32; ++i){
            float a = aa2L[i];
            WlsD[i*256 + tid] = pk2(a*W3[i*512 + c0*COUT_ + col], a*W3[i*512 + (c0+1)*COUT_ + col]);
        }
        float v0 = b3[c0*COUT_ + col], v1 = b3[(c0+1)*COUT_ + col];
        #pragma unroll 4
        for (int h = 0; h < H_; ++h){
            v0 = fmaf(bb2L[h], W3[h*512 + c0*COUT_ + col], v0);
            v1 = fmaf(bb2L[h], W3[h*512 + (c0+1)*COUT_ + col], v1);
        }
        WlsD[32*256 + tid] = pk2(v0, v1);
    }
    __syncthreads();

    const int rB = blockIdx.x*256 + w*64;
    const int blk0 = blockIdx.x*8 + w*2;

    union { uint4 u4; f16x8 v; } A0, A1;     // W2'^T A-frags
    A0.u4 = ((const uint4*)W2L)[lane];
    A1.u4 = ((const uint4*)W2L)[64 + lane];
    float b2v[16];
    #pragma unroll
    for (int i = 0; i < 16; ++i) b2v[i] = b2pL[(i&3) + 8*(i>>2) + 4*half];

    unsigned int h2p0[16], h2p1[16];
    unsigned int gsel0[4], gsel1[4];
    PHASEA(0, h2p0, gsel0);
    PHASEA(1, h2p1, gsel1);

    f32x16 acc0, acc1;
    #pragma unroll
    for (int i = 0; i < 16; ++i){ acc0[i] = 0.f; acc1[i] = 0.f; }
    #pragma unroll
    for (int kb = 0; kb < 32; ++kb){
        union { uint4 u4; f16x8 v; } bf; bf.u4 = Wls[kb*64 + lane];   // read ONCE, feeds both t
        const unsigned int sel = (kb & 1) ? 0x03020302u : 0x01000100u;
        unsigned int hr0 = h2p0[kb >> 1];
        unsigned int hd0 = __builtin_amdgcn_perm(hr0, hr0, sel);
        union { unsigned int u[4]; f16x8 v; } af;
        #pragma unroll
        for (int jj = 0; jj < 4; ++jj) af.u[jj] = pkmul(hd0, gsel0[jj]);
        acc0 = __builtin_amdgcn_mfma_f32_32x32x16_f16(af.v, bf.v, acc0, 0, 0, 0);
        unsigned int hr1 = h2p1[kb >> 1];
        unsigned int hd1 = __builtin_amdgcn_perm(hr1, hr1, sel);
        #pragma unroll
        for (int jj = 0; jj < 4; ++jj) af.u[jj] = pkmul(hd1, gsel1[jj]);
        acc1 = __builtin_amdgcn_mfma_f32_32x32x16_f16(af.v, bf.v, acc1, 0, 0, 0);
    }
    {   // bias step: A = gp, B = b3'
        union { uint4 u4; f16x8 v; } bf; bf.u4 = Wls[32*64 + lane];
        union { unsigned int u[4]; f16x8 v; } af;
        #pragma unroll
        for (int jj = 0; jj < 4; ++jj) af.u[jj] = gsel0[jj];
        acc0 = __builtin_amdgcn_mfma_f32_32x32x16_f16(af.v, bf.v, acc0, 0, 0, 0);
        #pragma unroll
        for (int jj = 0; jj < 4; ++jj) af.u[jj] = gsel1[jj];
        acc1 = __builtin_amdgcn_mfma_f32_32x32x16_f16(af.v, bf.v, acc1, 0, 0, 0);
    }

    REDST(acc0, 0);
    REDST(acc1, 1);

    __syncthreads();
    if (tid < COUT_){
        int sh = (blockIdx.x & (NSH-1)) * 32 + tid;     // shadowed s3/q3 (was 1024-deep RMW chain)
        atomicAdd(&s3s[sh], redS[tid]);
        atomicAdd(&q3s[sh], redQ[tid]);
    }
}

// ---- k_bn: per-channel aa/bb once in LDS (shadow-summed), then vectorized float4 apply ----
__global__ __launch_bounds__(256) void k_bn(const float4* __restrict__ out_pre4,
                                            const float* __restrict__ s3s, const float* __restrict__ q3s,
                                            const float* __restrict__ gbn, const float* __restrict__ bbn,
                                            float4* __restrict__ out4){
    __shared__ float aaL[COUT_], bbL[COUT_];
    const int tid = threadIdx.x;
    if (tid < COUT_){
        float ss = shsum(s3s, tid), qq = shsum(q3s, tid);
        float mm = ss*INVBN_, vv = qq*INVBN_ - mm*mm;
        float aa = gbn[tid]/sqrtf(vv + EPS_);
        aaL[tid] = aa;
        bbL[tid] = fmaf(-aa, mm, bbn[tid]);
    }
    __syncthreads();
    int i = blockIdx.x*256 + tid;                  // 65536 float4s
    int o = (i*4) & (COUT_-1);
    float4 v = out_pre4[i];
    float4 r;
    r.x = fmaf(aaL[o],   v.x, bbL[o]);
    r.y = fmaf(aaL[o+1], v.y, bbL[o+1]);
    r.z = fmaf(aaL[o+2], v.z, bbL[o+2]);
    r.w = fmaf(aaL[o+3], v.w, bbL[o+3]);
    out4[i] = r;
}

extern "C" void kernel_launch(void* const* d_in, const int* in_sizes, int n_in,
                              void* d_out, int out_size, void* d_ws, size_t ws_size,
                              hipStream_t stream){
    const float* xyz    = (const float*)d_in[0];
    const float* points = (const float*)d_in[1];
    const float* W1  = (const float*)d_in[2];
    const float* b1  = (const float*)d_in[3];
    const float* g1  = (const float*)d_in[4];
    const float* be1 = (const float*)d_in[5];
    const float* W2  = (const float*)d_in[6];
    const float* b2  = (const float*)d_in[7];
    const float* g2  = (const float*)d_in[8];
    const float* be2 = (const float*)d_in[9];
    const float* W3  = (const float*)d_in[10];
    const float* b3  = (const float*)d_in[11];
    const float* gbn = (const float*)d_in[12];
    const float* bbn = (const float*)d_in[13];
    float* out = (float*)d_out;

    // ws layout (bytes)
    char* base = (char*)d_ws;
    int*            idx     = (int*)(base + 0);                     // 1,048,576
    float*          out_pre = (float*)(base + 1048576);             // 1,048,576
    unsigned int*   pf16    = (unsigned int*)(base + 2097152);      //    262,144
    float*          st      = (float*)(base + 2359296);             //     12,288 (3072 floats)
    float4*         xs4g    = (float4*)(base + 2371584);            //    131,072
    unsigned int*   h1f     = (unsigned int*)(base + 4194304);      // 16,777,216 (R_*H_*2B, frag layout)
    // st floats (each 512 = NSH x 32 shadows): s1s | q1s | s2s | q2s | s3s | q3s
    float *s1s=st, *q1s=st+512, *s2s=st+1024, *q2s=st+1536, *s3s=st+2048, *q3s=st+2560;

    hipLaunchKernelGGL(k_prep0,   dim3(288),      dim3(256), 0, stream, xyz, points, xs4g, pf16, st);
    hipLaunchKernelGGL(k_knn,     dim3(B_*N_/4),  dim3(256), 0, stream, xs4g, W1, b1, idx, s1s, q1s, h1f);
    hipLaunchKernelGGL(k_h2stats, dim3(R_/512),   dim3(256), 0, stream, (const uint4*)h1f,
                       s1s, q1s, g1, be1, W2, b2, s2s, q2s);
    hipLaunchKernelGGL(k_out,     dim3(R_/256),   dim3(256), 0, stream, (const uint4*)h1f, idx,
                       s1s, q1s, g1, be1, W2, b2, s2s, q2s, g2, be2, W3, b3, pf16, out_pre, s3s, q3s);
    hipLaunchKernelGGL(k_bn,      dim3(256),      dim3(256), 0, stream, (const float4*)out_pre, s3s, q3s,
                       gbn, bbn, (float4*)out);
}

// Round 11
// 155.068 us; speedup vs baseline: 1.1254x; 1.0390x over previous
//
#include <hip/hip_runtime.h>

#define B_ 4
#define N_ 2048
#define K_ 32
#define CIN_ 16
#define COUT_ 32
#define H_ 32
#define R_ (B_*N_*K_)      // 262144 rows through the weight-net
#define EPS_ 1e-5f
#define INVR_ (1.0f/(float)R_)
#define INVBN_ (1.0f/(float)(B_*N_))
#define LISTCAP 160
#define NSH 16             // stat shadows (applied to ALL cross-block stat reductions)

typedef __attribute__((ext_vector_type(8)))  _Float16 f16x8;
typedef __attribute__((ext_vector_type(2)))  __fp16   hw16x2;   // builtin cvt_pkrtz return type
typedef __attribute__((ext_vector_type(2)))  _Float16 f16x2;
typedef __attribute__((ext_vector_type(16))) float    f32x16;

__device__ __forceinline__ float dot3f(float ax,float ay,float az,float bx,float by,float bz){
    return fmaf(az,bz, fmaf(ay,by, ax*bx));
}
__device__ __forceinline__ unsigned int pk2(float a, float b){   // packed f16 pair (RTZ)
    union { hw16x2 v; unsigned int u; } c;
    c.v = __builtin_amdgcn_cvt_pkrtz(a, b);
    return c.u;
}
__device__ __forceinline__ unsigned int pkmul(unsigned int a, unsigned int b){  // v_pk_mul_f16
    union { unsigned int u; f16x2 v; } x, y, r;
    x.u = a; y.u = b; r.v = x.v * y.v; return r.u;
}
// sum of NSH shadow accumulators
__device__ __forceinline__ float shsum(const float* __restrict__ p, int k){
    float s = 0.f;
    #pragma unroll
    for (int i = 0; i < NSH; ++i) s += p[i*32 + k];
    return s;
}

// ---------------- KNN: 1 wave/query, SELF-STAGED xyz in LDS (prep0 eliminated) ----------------
// Candidates live in conflict-free SoA LDS (sx/sy/sz, 24KB; bank = lane%32, 2-way = free).
// |p|^2 recomputed per candidate with the IDENTICAL dot3f chain prep0 used -> bit-identical d
// -> identical top-K. (256,3): LDS 45.5KB caps at 3 blocks/CU anyway; VGPR cap ~170 so fv[32]
// stays in true VGPRs (no AGPR copies, no scratch). knn occupancy-insensitivity proven R4-R9.
__global__ __launch_bounds__(256,3) void k_knn(const float* __restrict__ xyz,
                                               const float* __restrict__ W1, const float* __restrict__ b1,
                                               int* __restrict__ idx_out,
                                               float* __restrict__ s1sh, float* __restrict__ q1sh,
                                               unsigned int* __restrict__ h1f){
    __shared__ float sx[N_], sy[N_], sz[N_];          // 24 KB SoA candidate cache
    __shared__ unsigned int hist[4][512][2];          // 16 KB: per-wave 512 buckets x2 replicas
    __shared__ unsigned long long lst[4][LISTCAP];    // 5 KB
    __shared__ int kidx[4][K_];                       // 0.5 KB

    const int tid  = threadIdx.x;
    const int w    = tid >> 6;
    const int lane = tid & 63;
    const int half = lane >> 5;
    const int b    = blockIdx.x >> 9;
    const int q    = ((blockIdx.x & 511) << 2) + w;
    const int bN   = b * N_;
    unsigned int* hw = &hist[w][0][0];

    // stage this batch's xyz -> SoA LDS (coalesced float4, deinterleave 3-float points)
    {
        const float4* xb4 = (const float4*)(xyz + (size_t)bN*3);   // 24576B, 16B-aligned
        for (int k = tid; k < (N_*3)/4; k += 256){
            float4 f = xb4[k];
            int base = 4*k;
            #pragma unroll
            for (int j = 0; j < 4; ++j){
                int g = base + j;
                int pt = g/3, cp = g - pt*3;
                float v = (j==0) ? f.x : (j==1) ? f.y : (j==2) ? f.z : f.w;
                if (cp == 0) sx[pt] = v;
                else if (cp == 1) sy[pt] = v;
                else sz[pt] = v;
            }
        }
    }

    const uint4 z4 = make_uint4(0,0,0,0);
    uint4* h4 = (uint4*)hw;                           // 256 uint4 per wave (per-wave private, no sync)
    #pragma unroll
    for (int i = 0; i < 4; ++i) h4[i*64 + lane] = z4;

    __syncthreads();                                  // staging complete (s_barrier only, no fence)

    const float qx = sx[q], qy = sy[q], qz = sz[q];
    const float sqq = dot3f(qx,qy,qz,qx,qy,qz);       // same chain prep0 used -> same bits

    // pass 1: 32 candidates/lane from LDS, cache d-bits, linear histogram
    unsigned int fv[32];
    #pragma unroll
    for (int j = 0; j < 32; ++j){
        int c = j*64 + lane;
        float px = sx[c], py = sy[c], pz = sz[c];
        float pw = dot3f(px,py,pz,px,py,pz);
        float d = fmaf(-2.0f, dot3f(qx,qy,qz,px,py,pz), sqq) + pw;
        fv[j] = __float_as_uint(d);
        unsigned int u1 = __float_as_uint(d + 1.0f);
        unsigned int key = (u1 <= 0x3F800000u) ? 0u : ((u1 - 0x3F800000u) >> 15);
        key = key > 511u ? 511u : key;
        atomicAdd(&hw[key*2 + (lane & 1)], 1u);
    }

    // select: smallest bucket with cumulative >= K (lane covers 8 buckets)
    unsigned int g[8];
    #pragma unroll
    for (int t = 0; t < 4; ++t){
        uint4 h = ((const uint4*)hw)[lane*4 + t];
        g[2*t]   = h.x + h.y;
        g[2*t+1] = h.z + h.w;
    }
    unsigned int gs = 0;
    #pragma unroll
    for (int t = 0; t < 8; ++t) gs += g[t];
    unsigned int cum = gs;
    #pragma unroll
    for (int off = 1; off < 64; off <<= 1){
        unsigned int v = __shfl_up(cum, off);
        if (lane >= off) cum += v;
    }
    unsigned long long bal = __ballot(cum >= (unsigned)K_);
    int L = __ffsll(bal) - 1;
    unsigned int run = __shfl(cum, L) - __shfl(gs, L);
    int Bsel = 8*L + 7;
    {
        unsigned int c = run; bool fnd = false;
        #pragma unroll
        for (int t = 0; t < 8; ++t){
            unsigned int ht = __shfl(g[t], L, 64);
            if (!fnd && c + ht >= (unsigned)K_){ Bsel = 8*L + t; fnd = true; }
            c += ht;
        }
    }
    const float Tedge = __uint_as_float(0x3F800000u + ((unsigned)(Bsel + 1) << 15));
    const bool allin = (Bsel == 511);

    // pass 2: ballot-compaction of survivors (f1 < Tedge <=> bucket <= Bsel)
    const unsigned long long mlt = (lane == 63) ? ~0ull >> 1 : (1ull << lane) - 1ull;
    unsigned int cnt = 0;
    #pragma unroll
    for (int j = 0; j < 32; ++j){
        float f1 = __uint_as_float(fv[j]) + 1.0f;
        bool surv = (f1 < Tedge) || allin;
        unsigned long long sb = __ballot(surv);
        unsigned int pos = cnt + (unsigned int)__popcll(sb & mlt);
        if (surv && pos < (unsigned)LISTCAP)
            lst[w][pos] = ((unsigned long long)fv[j] << 32) | (unsigned int)(j*64 + lane);
        cnt += (unsigned int)__popcll(sb);
    }
    int m = (int)cnt; if (m > LISTCAP) m = LISTCAP;

    // rank-select (keys unique: idx in low bits) -> exact top_k tie-break
    int* outp = idx_out + ((size_t)bN + q) * K_;
    for (int i = lane; i < m; i += 64){
        unsigned long long my = lst[w][i];
        int rank = 0;
        for (int jj = 0; jj < m; ++jj)
            rank += (lst[w][jj] < my) ? 1 : 0;
        if (rank < K_){
            int id = (int)(unsigned int)(my & 0xFFFFFFFFull);
            outp[rank] = id;
            kidx[w][rank] = id;
        }
    }

    // fused h1 stats: ch = lane&31; halves split the 32 neighbors (16 each)
    {
        const int ch = lane & 31;
        float w1a = W1[ch], w1b = W1[H_+ch], w1c = W1[2*H_+ch], b1c = b1[ch];
        float s = 0.f, qq = 0.f;
        #pragma unroll
        for (int r = 0; r < 16; ++r){
            int idr = kidx[w][half*16 + r];            // wave-uniform LDS broadcast
            float rx = sx[idr] - qx, ry = sy[idr] - qy, rz = sz[idr] - qz;
            float h = fmaxf(fmaf(rx, w1a, fmaf(ry, w1b, fmaf(rz, w1c, b1c))), 0.0f);
            s += h; qq = fmaf(h, h, qq);
        }
        s  += __shfl_xor(s, 32, 64);
        qq += __shfl_xor(qq, 32, 64);
        if (lane < 32){
            int sh = (blockIdx.x & (NSH-1)) * 32 + ch;
            atomicAdd(&s1sh[sh], s);
            atomicAdd(&q1sh[sh], qq);
        }
    }

    // ---- h1 -> global in MFMA fragment layout: lane = (row lane&31, ch-block (lane>>5)*8) ----
    {
        const int id = kidx[w][lane & 31];
        float rx = sx[id] - qx, ry = sy[id] - qy, rz = sz[id] - qz;
        uint4* dst = (uint4*)h1f + (size_t)(bN + q)*128 + lane;
        const int c0 = half*8;
        #pragma unroll
        for (int sblk = 0; sblk < 2; ++sblk){
            const int cb = sblk*16 + c0;
            const float4 wa0 = *(const float4*)(W1 + cb);
            const float4 wa1 = *(const float4*)(W1 + cb + 4);
            const float4 wb0 = *(const float4*)(W1 + H_ + cb);
            const float4 wb1 = *(const float4*)(W1 + H_ + cb + 4);
            const float4 wc0 = *(const float4*)(W1 + 2*H_ + cb);
            const float4 wc1 = *(const float4*)(W1 + 2*H_ + cb + 4);
            const float4 bv0 = *(const float4*)(b1 + cb);
            const float4 bv1 = *(const float4*)(b1 + cb + 4);
            float h0 = fmaxf(fmaf(rx, wa0.x, fmaf(ry, wb0.x, fmaf(rz, wc0.x, bv0.x))), 0.0f);
            float h1v= fmaxf(fmaf(rx, wa0.y, fmaf(ry, wb0.y, fmaf(rz, wc0.y, bv0.y))), 0.0f);
            float h2v= fmaxf(fmaf(rx, wa0.z, fmaf(ry, wb0.z, fmaf(rz, wc0.z, bv0.z))), 0.0f);
            float h3 = fmaxf(fmaf(rx, wa0.w, fmaf(ry, wb0.w, fmaf(rz, wc0.w, bv0.w))), 0.0f);
            float h4 = fmaxf(fmaf(rx, wa1.x, fmaf(ry, wb1.x, fmaf(rz, wc1.x, bv1.x))), 0.0f);
            float h5 = fmaxf(fmaf(rx, wa1.y, fmaf(ry, wb1.y, fmaf(rz, wc1.y, bv1.y))), 0.0f);
            float h6 = fmaxf(fmaf(rx, wa1.z, fmaf(ry, wb1.z, fmaf(rz, wc1.z, bv1.z))), 0.0f);
            float h7 = fmaxf(fmaf(rx, wa1.w, fmaf(ry, wb1.w, fmaf(rz, wc1.w, bv1.w))), 0.0f);
            uint4 o;
            o.x = pk2(h0, h1v); o.y = pk2(h2v, h3); o.z = pk2(h4, h5); o.w = pk2(h6, h7);
            dst[sblk*64] = o;
        }
    }
}

// ---- shared head: BN1 scale/shift + W2f frags + b2p into LDS (bit-identical to old k_prep2) ----
__device__ __forceinline__ void build_l2(const float* __restrict__ s1s, const float* __restrict__ q1s,
                                         const float* __restrict__ g1, const float* __restrict__ be1,
                                         const float* __restrict__ W2, const float* __restrict__ b2,
                                         float* a1L, float* bb1L, unsigned int* W2L, float* b2pL,
                                         int tid){
    if (tid < H_){
        float s = shsum(s1s, tid), qq = shsum(q1s, tid);
        float mm = s*INVR_, vv = qq*INVR_ - mm*mm;
        float aa = g1[tid] / sqrtf(vv + EPS_);
        a1L[tid]  = aa;
        bb1L[tid] = fmaf(-aa, mm, be1[tid]);
    }
    __syncthreads();
    #pragma unroll
    for (int e = 0; e < 2; ++e){
        int d = tid*2 + e;
        int jj = d & 3, ln = (d >> 2) & 63, s = d >> 8;
        int col = ln & 31;
        int k0 = s*16 + ((ln >> 5) << 3) + 2*jj;
        W2L[d] = pk2(a1L[k0]*W2[k0*H_ + col], a1L[k0+1]*W2[(k0+1)*H_ + col]);
    }
    if (tid < H_){
        float acc = b2[tid];
        #pragma unroll 4
        for (int h = 0; h < H_; ++h) acc = fmaf(bb1L[h], W2[h*H_ + tid], acc);
        b2pL[tid] = acc;
    }
}

// ---- k_h2stats (+fused prep2 +pf16 convert): h1-frags -> layer2 MFMA -> relu -> channel stats ----
__global__ __launch_bounds__(256,4) void k_h2stats(const uint4* __restrict__ h1f,
                                                   const float* __restrict__ points, unsigned int* __restrict__ pf16,
                                                   const float* __restrict__ s1s, const float* __restrict__ q1s,
                                                   const float* __restrict__ g1, const float* __restrict__ be1,
                                                   const float* __restrict__ W2, const float* __restrict__ b2,
                                                   float* s2s, float* q2s){
    __shared__ float redS[H_], redQ[H_];
    __shared__ float a1L[H_], bb1L[H_], b2pL[H_];
    __shared__ unsigned int W2L[512];
    const int tid = threadIdx.x, lane = tid & 63, w = tid >> 6;
    const int m = lane & 31;
    // pf16 conversion (prep0's old job; consumed only by the NEXT dispatch, k_out)
    {
        int pp = blockIdx.x*256 + tid;
        if (pp < 65536) pf16[pp] = pk2(points[2*pp], points[2*pp+1]);
    }
    if (tid < H_){ redS[tid] = 0.f; redQ[tid] = 0.f; }
    build_l2(s1s, q1s, g1, be1, W2, b2, a1L, bb1L, W2L, b2pL, tid);
    __syncthreads();

    union { uint4 u4; f16x8 v; } Bf0, Bf1;
    Bf0.u4 = ((const uint4*)W2L)[lane];
    Bf1.u4 = ((const uint4*)W2L)[64 + lane];
    float b2c = b2pL[m];
    const int blk0 = blockIdx.x*16 + w*4;

    float s = 0.f, q = 0.f;
    #pragma unroll
    for (int t = 0; t < 4; ++t){
        union { uint4 u4; f16x8 v; } a0, a1f;
        a0.u4  = h1f[(size_t)(blk0 + t)*128 + lane];
        a1f.u4 = h1f[(size_t)(blk0 + t)*128 + 64 + lane];
        f32x16 acc;
        #pragma unroll
        for (int i = 0; i < 16; ++i) acc[i] = b2c;
        acc = __builtin_amdgcn_mfma_f32_32x32x16_f16(a0.v,  Bf0.v, acc, 0, 0, 0);
        acc = __builtin_amdgcn_mfma_f32_32x32x16_f16(a1f.v, Bf1.v, acc, 0, 0, 0);
        #pragma unroll
        for (int i = 0; i < 16; ++i){
            float v = fmaxf(acc[i], 0.0f);
            s += v; q = fmaf(v, v, q);
        }
    }
    s += __shfl_xor(s, 32, 64);
    q += __shfl_xor(q, 32, 64);
    if (lane < 32){ atomicAdd(&redS[m], s); atomicAdd(&redQ[m], q); }
    __syncthreads();
    if (tid < H_){
        int sh = (blockIdx.x & (NSH-1)) * 32 + tid;
        atomicAdd(&s2s[sh], redS[tid]);
        atomicAdd(&q2s[sh], redQ[tid]);
    }
}

// ---- k_out (+fused prep2+prep3): builds W2f/b2p AND W3f in-block, then the fused 2-layer MFMA ----
#define PHASEA(T, H2P, GSEL) do { \
    union { uint4 u4; f16x8 v; } B0f, B1f; \
    B0f.u4 = h1f[(size_t)(blk0 + (T))*128 + lane]; \
    B1f.u4 = h1f[(size_t)(blk0 + (T))*128 + 64 + lane]; \
    int row = rB + (T)*32 + m; \
    int bb_ = row >> 16; \
    int idr = idx[row]; \
    const uint4* gpp = (const uint4*)(pf16 + ((size_t)bb_*N_ + idr)*8); \
    uint4 ga = gpp[0], gb = gpp[1]; \
    GSEL[0] = half ? gb.x : ga.x; \
    GSEL[1] = half ? gb.y : ga.y; \
    GSEL[2] = half ? gb.z : ga.z; \
    GSEL[3] = half ? gb.w : ga.w; \
    f32x16 c2; \
    _Pragma("unroll") \
    for (int i = 0; i < 16; ++i) c2[i] = b2v[i]; \
    c2 = __builtin_amdgcn_mfma_f32_32x32x16_f16(A0.v, B0f.v, c2, 0, 0, 0); \
    c2 = __builtin_amdgcn_mfma_f32_32x32x16_f16(A1.v, B1f.v, c2, 0, 0, 0); \
    _Pragma("unroll") \
    for (int p = 0; p < 8; ++p){ \
        float v0 = fmaxf(c2[2*p],   0.0f); \
        float v1 = fmaxf(c2[2*p+1], 0.0f); \
        unsigned int ow = pk2(v0, v1); \
        unsigned int ot = __shfl_xor(ow, 32, 64); \
        int a = p >> 1, bb = p & 1; \
        H2P[4*a + bb]     = half ? ot : ow; \
        H2P[4*a + 2 + bb] = half ? ow : ot; \
    } \
} while(0)

#define REDST(ACC, T) do { \
    float v = ACC[0]; \
    _Pragma("unroll") \
    for (int i = 1; i < 16; ++i) v = fmaxf(v, ACC[i]); \
    v = fmaxf(v, __shfl_xor(v, 32, 64)); \
    if (lane < 32){ \
        int g = blk0 + (T); \
        out_pre[(size_t)g*COUT_ + m] = v; \
        atomicAdd(&redS[m], v); \
        atomicAdd(&redQ[m], v*v); \
    } \
} while(0)

__global__ __launch_bounds__(256,4) void k_out(const uint4* __restrict__ h1f, const int* __restrict__ idx,
                                               const float* __restrict__ s1s, const float* __restrict__ q1s,
                                               const float* __restrict__ g1, const float* __restrict__ be1,
                                               const float* __restrict__ W2, const float* __restrict__ b2,
                                               const float* __restrict__ s2s, const float* __restrict__ q2s,
                                               const float* __restrict__ g2, const float* __restrict__ be2,
                                               const float* __restrict__ W3, const float* __restrict__ b3,
                                               const unsigned int* __restrict__ pf16,
                                               float* __restrict__ out_pre, float* s3s, float* q3s){
    __shared__ uint4 Wls[2112];                      // 33 KB: W3f fragments (built in-block)
    __shared__ float redS[COUT_], redQ[COUT_];
    __shared__ float a1L[H_], bb1L[H_], b2pL[H_], aa2L[H_], bb2L[H_];
    __shared__ unsigned int W2L[512];
    const int tid = threadIdx.x, lane = tid & 63, w = tid >> 6;
    const int half = lane >> 5, m = lane & 31;
    if (tid < COUT_){
        redS[tid] = 0.f; redQ[tid] = 0.f;
        float ss = shsum(s2s, tid), qq = shsum(q2s, tid);   // shadow-summed s2/q2
        float mm = ss*INVR_, vv = qq*INVR_ - mm*mm;
        float aa = g2[tid] / sqrtf(vv + EPS_);
        aa2L[tid] = aa;
        bb2L[tid] = fmaf(-aa, mm, be2[tid]);
    }
    build_l2(s1s, q1s, g1, be1, W2, b2, a1L, bb1L, W2L, b2pL, tid);
    {   // W3f -> Wls (identical dword mapping + arithmetic to old k_prep3)
        int jj = tid & 3, ln = tid >> 2;
        int col = ln & 31, c0 = ((ln >> 5) << 3) + 2*jj;
        unsigned int* WlsD = (unsigned int*)Wls;
        #pragma unroll 4
        for (int i = 0; i < 32; ++i){
            float a = aa2L[i];
            WlsD[i*256 + tid] = pk2(a*W3[i*512 + c0*COUT_ + col], a*W3[i*512 + (c0+1)*COUT_ + col]);
        }
        float v0 = b3[c0*COUT_ + col], v1 = b3[(c0+1)*COUT_ + col];
        #pragma unroll 4
        for (int h = 0; h < H_; ++h){
            v0 = fmaf(bb2L[h], W3[h*512 + c0*COUT_ + col], v0);
            v1 = fmaf(bb2L[h], W3[h*512 + (c0+1)*COUT_ + col], v1);
        }
        WlsD[32*256 + tid] = pk2(v0, v1);
    }
    __syncthreads();

    const int rB = blockIdx.x*256 + w*64;
    const int blk0 = blockIdx.x*8 + w*2;

    union { uint4 u4; f16x8 v; } A0, A1;     // W2'^T A-frags
    A0.u4 = ((const uint4*)W2L)[lane];
    A1.u4 = ((const uint4*)W2L)[64 + lane];
    float b2v[16];
    #pragma unroll
    for (int i = 0; i < 16; ++i) b2v[i] = b2pL[(i&3) + 8*(i>>2) + 4*half];

    unsigned int h2p0[16], h2p1[16];
    unsigned int gsel0[4], gsel1[4];
    PHASEA(0, h2p0, gsel0);
    PHASEA(1, h2p1, gsel1);

    f32x16 acc0, acc1;
    #pragma unroll
    for (int i = 0; i < 16; ++i){ acc0[i] = 0.f; acc1[i] = 0.f; }
    #pragma unroll
    for (int kb = 0; kb < 32; ++kb){
        union { uint4 u4; f16x8 v; } bf; bf.u4 = Wls[kb*64 + lane];   // read ONCE, feeds both t
        const unsigned int sel = (kb & 1) ? 0x03020302u : 0x01000100u;
        unsigned int hr0 = h2p0[kb >> 1];
        unsigned int hd0 = __builtin_amdgcn_perm(hr0, hr0, sel);
        union { unsigned int u[4]; f16x8 v; } af;
        #pragma unroll
        for (int jj = 0; jj < 4; ++jj) af.u[jj] = pkmul(hd0, gsel0[jj]);
        acc0 = __builtin_amdgcn_mfma_f32_32x32x16_f16(af.v, bf.v, acc0, 0, 0, 0);
        unsigned int hr1 = h2p1[kb >> 1];
        unsigned int hd1 = __builtin_amdgcn_perm(hr1, hr1, sel);
        #pragma unroll
        for (int jj = 0; jj < 4; ++jj) af.u[jj] = pkmul(hd1, gsel1[jj]);
        acc1 = __builtin_amdgcn_mfma_f32_32x32x16_f16(af.v, bf.v, acc1, 0, 0, 0);
    }
    {   // bias step: A = gp, B = b3'
        union { uint4 u4; f16x8 v; } bf; bf.u4 = Wls[32*64 + lane];
        union { unsigned int u[4]; f16x8 v; } af;
        #pragma unroll
        for (int jj = 0; jj < 4; ++jj) af.u[jj] = gsel0[jj];
        acc0 = __builtin_amdgcn_mfma_f32_32x32x16_f16(af.v, bf.v, acc0, 0, 0, 0);
        #pragma unroll
        for (int jj = 0; jj < 4; ++jj) af.u[jj] = gsel1[jj];
        acc1 = __builtin_amdgcn_mfma_f32_32x32x16_f16(af.v, bf.v, acc1, 0, 0, 0);
    }

    REDST(acc0, 0);
    REDST(acc1, 1);

    __syncthreads();
    if (tid < COUT_){
        int sh = (blockIdx.x & (NSH-1)) * 32 + tid;     // shadowed s3/q3
        atomicAdd(&s3s[sh], redS[tid]);
        atomicAdd(&q3s[sh], redQ[tid]);
    }
}

// ---- k_bn: per-channel aa/bb once in LDS (shadow-summed), then vectorized float4 apply ----
__global__ __launch_bounds__(256) void k_bn(const float4* __restrict__ out_pre4,
                                            const float* __restrict__ s3s, const float* __restrict__ q3s,
                                            const float* __restrict__ gbn, const float* __restrict__ bbn,
                                            float4* __restrict__ out4){
    __shared__ float aaL[COUT_], bbL[COUT_];
    const int tid = threadIdx.x;
    if (tid < COUT_){
        float ss = shsum(s3s, tid), qq = shsum(q3s, tid);
        float mm = ss*INVBN_, vv = qq*INVBN_ - mm*mm;
        float aa = gbn[tid]/sqrtf(vv + EPS_);
        aaL[tid] = aa;
        bbL[tid] = fmaf(-aa, mm, bbn[tid]);
    }
    __syncthreads();
    int i = blockIdx.x*256 + tid;                  // 65536 float4s
    int o = (i*4) & (COUT_-1);
    float4 v = out_pre4[i];
    float4 r;
    r.x = fmaf(aaL[o],   v.x, bbL[o]);
    r.y = fmaf(aaL[o+1], v.y, bbL[o+1]);
    r.z = fmaf(aaL[o+2], v.z, bbL[o+2]);
    r.w = fmaf(aaL[o+3], v.w, bbL[o+3]);
    out4[i] = r;
}

extern "C" void kernel_launch(void* const* d_in, const int* in_sizes, int n_in,
                              void* d_out, int out_size, void* d_ws, size_t ws_size,
                              hipStream_t stream){
    const float* xyz    = (const float*)d_in[0];
    const float* points = (const float*)d_in[1];
    const float* W1  = (const float*)d_in[2];
    const float* b1  = (const float*)d_in[3];
    const float* g1  = (const float*)d_in[4];
    const float* be1 = (const float*)d_in[5];
    const float* W2  = (const float*)d_in[6];
    const float* b2  = (const float*)d_in[7];
    const float* g2  = (const float*)d_in[8];
    const float* be2 = (const float*)d_in[9];
    const float* W3  = (const float*)d_in[10];
    const float* b3  = (const float*)d_in[11];
    const float* gbn = (const float*)d_in[12];
    const float* bbn = (const float*)d_in[13];
    float* out = (float*)d_out;

    // ws layout (bytes)
    char* base = (char*)d_ws;
    int*            idx     = (int*)(base + 0);                     // 1,048,576
    float*          out_pre = (float*)(base + 1048576);             // 1,048,576
    unsigned int*   pf16    = (unsigned int*)(base + 2097152);      //    262,144
    float*          st      = (float*)(base + 2359296);             //     12,288 (3072 floats)
    unsigned int*   h1f     = (unsigned int*)(base + 4194304);      // 16,777,216 (R_*H_*2B, frag layout)
    // st floats (each 512 = NSH x 32 shadows): s1s | q1s | s2s | q2s | s3s | q3s
    float *s1s=st, *q1s=st+512, *s2s=st+1024, *q2s=st+1536, *s3s=st+2048, *q3s=st+2560;

    // stat zeroing: stream-ordered async memset (graph-capturable; replaces prep0's zero loop)
    hipMemsetAsync((void*)st, 0, 12288, stream);

    hipLaunchKernelGGL(k_knn,     dim3(B_*N_/4),  dim3(256), 0, stream, xyz, W1, b1, idx, s1s, q1s, h1f);
    hipLaunchKernelGGL(k_h2stats, dim3(R_/512),   dim3(256), 0, stream, (const uint4*)h1f,
                       points, pf16, s1s, q1s, g1, be1, W2, b2, s2s, q2s);
    hipLaunchKernelGGL(k_out,     dim3(R_/256),   dim3(256), 0, stream, (const uint4*)h1f, idx,
                       s1s, q1s, g1, be1, W2, b2, s2s, q2s, g2, be2, W3, b3, pf16, out_pre, s3s, q3s);
    hipLaunchKernelGGL(k_bn,      dim3(256),      dim3(256), 0, stream, (const float4*)out_pre, s3s, q3s,
                       gbn, bbn, (float4*)out);
}